// Round 17
// baseline (119.892 us; speedup 1.0000x reference)
//
#include <hip/hip_runtime.h>
#include <hip/hip_bf16.h>
#include <stdint.h>

// out = (QK^T/sqrt(d))V = Q (K^T V)/sqrt(d)   (no softmax in ref)
// F = Wq^T Wk;  G = x^T x (symmetric);  H = F G;
// Pt = [Wv H^T + bv a1^T + w a2^T + L bv a2^T]/sqrt(d)
// r[z,o] = [Wv·g + cs bv + bb (w + L bv)]/sqrt(d);  out = xb Pt^T + 1 r^T
// Round-17: G = split-K x2 over 12 upper-tri tiles (192 blocks, wall ~13us)
// + lean f32 reduce/mirror kernel; GEMVs moved to a no-LDS vec_k.

typedef __attribute__((ext_vector_type(8))) short short8;
typedef __attribute__((ext_vector_type(8))) unsigned short ushort8;
typedef __attribute__((ext_vector_type(4))) float f32x4;
typedef __attribute__((address_space(3))) void lds_void;
typedef const __attribute__((address_space(1))) void gmem_void;

#define WAITV(n) asm volatile("s_waitcnt vmcnt(" #n ")" ::: "memory")

__device__ __forceinline__ unsigned short f2bf(float f) {
  union { float f; unsigned u; } v; v.f = f;
  unsigned r = v.u + 0x7fff + ((v.u >> 16) & 1);   // RNE
  return (unsigned short)(r >> 16);
}
__device__ __forceinline__ float bf2f(unsigned short u) {
  union { unsigned u; float f; } v; v.u = ((unsigned)u) << 16; return v.f;
}
__device__ __forceinline__ float wave_red(float a) {
#pragma unroll
  for (int off = 32; off; off >>= 1) a += __shfl_down(a, off);
  return a;
}

// ---------------- preamble: x->xt,xb,col-partials; Wq^T,Wk^T,Wv casts -------
__global__ __launch_bounds__(256) void preamble(
    const float* __restrict__ x, const float* __restrict__ Wq,
    const float* __restrict__ Wk, const float* __restrict__ Wv,
    unsigned short* __restrict__ xb, unsigned short* __restrict__ xt,
    unsigned short* __restrict__ wqtb, unsigned short* __restrict__ wktb,
    unsigned short* __restrict__ wvb, float* __restrict__ partials)
{
  const int bid = blockIdx.x;
  const int tid = threadIdx.x;
  if (bid < 3072) {                       // x role: 64l x 64d tile
    __shared__ float tile[64][65];
    __shared__ float pt4[4][64];
    const int z = bid / 384, rem = bid % 384;
    const int l0 = (rem / 12) * 64, d0 = (rem % 12) * 64;
    const int tx = tid & 63, ty = tid >> 6;
    const float* xz = x + ((long)z * 2048 + l0) * 768 + d0;
    float colacc = 0.f;
#pragma unroll
    for (int i = 0; i < 16; ++i) {
      const int l = i * 4 + ty;
      float v = xz[(long)l * 768 + tx];
      tile[l][tx] = v;
      colacc += v;
    }
    pt4[ty][tx] = colacc;
    __syncthreads();
    if (ty == 0)
      partials[((long)z * 768 + d0 + tx) * 32 + (l0 >> 6)] =
          pt4[0][tx] + pt4[1][tx] + pt4[2][tx] + pt4[3][tx];
    unsigned short* xbz = xb + ((long)z * 2048 + l0) * 768 + d0;
    const int jr = tid & 7, rw = tid >> 3;
#pragma unroll
    for (int it = 0; it < 2; ++it) {
      const int row = it * 32 + rw;
      unsigned short o[8];
#pragma unroll
      for (int e = 0; e < 8; ++e) o[e] = f2bf(tile[row][jr * 8 + e]);
      *(ushort8*)(xbz + (long)row * 768 + jr * 8) = *(ushort8*)o;
    }
    unsigned short* xtz = xt + ((long)z * 768 + d0) * 2048 + l0;
#pragma unroll
    for (int it = 0; it < 2; ++it) {
      const int d = it * 32 + rw;
      unsigned short o[8];
#pragma unroll
      for (int e = 0; e < 8; ++e) o[e] = f2bf(tile[jr * 8 + e][d]);
      *(ushort8*)(xtz + (long)d * 2048 + jr * 8) = *(ushort8*)o;
    }
  } else if (bid < 4224) {                // weight transpose (wq, wk)
    __shared__ float tl[32][33];
    int t = bid - 3072;
    const float* W = (t < 576) ? Wq : Wk;
    unsigned short* O = (t < 576) ? wqtb : wktb;
    t = (t >= 576) ? t - 576 : t;
    const int r0 = (t / 24) * 32, c0 = (t % 24) * 32;
    const int tx = tid & 31, ty = tid >> 5;
    for (int i = ty; i < 32; i += 8) tl[i][tx] = W[(long)(r0 + i) * 768 + c0 + tx];
    __syncthreads();
    for (int i = ty; i < 32; i += 8) O[(long)(c0 + i) * 768 + r0 + tx] = f2bf(tl[tx][i]);
  } else {                                // wv cast
    const int t = bid - 4224;
    const long i = ((long)t * 256 + tid) * 8;
    float4 v0 = *(const float4*)(Wv + i);
    float4 v1 = *(const float4*)(Wv + i + 4);
    unsigned short o[8];
    o[0] = f2bf(v0.x); o[1] = f2bf(v0.y); o[2] = f2bf(v0.z); o[3] = f2bf(v0.w);
    o[4] = f2bf(v1.x); o[5] = f2bf(v1.y); o[6] = f2bf(v1.z); o[7] = f2bf(v1.w);
    *(ushort8*)(wvb + i) = *(ushort8*)o;
  }
}

// -------- 256^2 8-phase counted-vmcnt core (T3+T4).  512 thr, 8 waves ------
template<int BIAS_MODE, int OUT_BF16>
__device__ __forceinline__ void gemm256_core(
    int z, long bm, long bn, unsigned short* __restrict__ lds,
    const unsigned short* __restrict__ A, const unsigned short* __restrict__ B,
    const float* __restrict__ bias, const float* __restrict__ b2,
    const float* __restrict__ b3, const float* __restrict__ b4,
    void* __restrict__ Cv,
    int K, int lda, int ldb, int ldc,
    long a_bs, long b_bs, long c_bs, long bias_bs, float scale)
{
  const int tid  = threadIdx.x;
  const int w    = tid >> 6;
  const int lane = tid & 63;
  const int wm   = w >> 2, wn = w & 3;
  const int fr   = lane & 15, kq = lane >> 4;
  const int srow = lane >> 3;
  const int schunk = (((lane & 7) ^ srow)) << 3;

  const unsigned short* Ab = A + (long)z * a_bs;
  const unsigned short* Bb = B + (long)z * b_bs;

  f32x4 acc[8][4];
#pragma unroll
  for (int r = 0; r < 8; ++r)
#pragma unroll
    for (int c = 0; c < 4; ++c) acc[r][c] = (f32x4){0.f, 0.f, 0.f, 0.f};

#define STG_A(p_, s_, k_) do { \
  _Pragma("unroll") for (int j_ = 0; j_ < 2; ++j_) { \
    const int idx_ = (w << 1) + j_; \
    const int grp_ = (idx_ < 8 ? idx_ : idx_ + 8) + (s_) * 8; \
    const unsigned short* g_ = Ab + (bm + grp_ * 8 + srow) * (long)lda + (k_) * 64 + schunk; \
    __builtin_amdgcn_global_load_lds((gmem_void*)g_, (lds_void*)(lds + (p_) * 32768 + grp_ * 512), 16, 0, 0); \
  } } while (0)
#define STG_B(p_, s_, k_) do { \
  _Pragma("unroll") for (int j_ = 0; j_ < 2; ++j_) { \
    const int idx_ = (w << 1) + j_; \
    const int grp_ = ((idx_ >> 2) << 3) + (idx_ & 3) + (s_) * 4; \
    const unsigned short* g_ = Bb + (bn + grp_ * 8 + srow) * (long)ldb + (k_) * 64 + schunk; \
    __builtin_amdgcn_global_load_lds((gmem_void*)g_, (lds_void*)(lds + (p_) * 32768 + 16384 + grp_ * 512), 16, 0, 0); \
  } } while (0)

  const int nk = K / 64;
  STG_A(0, 0, 0); STG_A(0, 1, 0); STG_B(0, 0, 0); STG_B(0, 1, 0);
  STG_A(1, 0, 1); STG_A(1, 1, 1); STG_B(1, 0, 1); STG_B(1, 1, 1);
  WAITV(8);
  __builtin_amdgcn_s_barrier();

  for (int k = 0; k < nk; ++k) {
    const int p = k & 1;
#pragma unroll
    for (int q = 0; q < 4; ++q) {
      const int mh = q >> 1, nh = q & 1;
      short8 af[4][2], bfv[2][2];
#pragma unroll
      for (int r = 0; r < 4; ++r)
#pragma unroll
        for (int ks = 0; ks < 2; ++ks) {
          const int arow = wm * 128 + mh * 64 + r * 16 + fr;
          af[r][ks] = *(const short8*)(lds + p * 32768 + arow * 64 +
                                       ((((ks << 2) + kq) ^ (arow & 7)) << 3));
        }
#pragma unroll
      for (int c = 0; c < 2; ++c)
#pragma unroll
        for (int ks = 0; ks < 2; ++ks) {
          const int brow = wn * 64 + nh * 32 + c * 16 + fr;
          bfv[c][ks] = *(const short8*)(lds + p * 32768 + 16384 + brow * 64 +
                                        ((((ks << 2) + kq) ^ (brow & 7)) << 3));
        }
      if (q == 0)      { if (k >= 1 && k + 1 < nk) STG_A((k + 1) & 1, 1, k + 1); }
      else if (q == 1) { if (k >= 1 && k + 1 < nk) STG_B((k + 1) & 1, 1, k + 1); }
      else if (q == 2) { if (k + 2 < nk) STG_A(p, 0, k + 2); }
      else             { if (k + 2 < nk) STG_B(p, 0, k + 2); }

      __builtin_amdgcn_s_barrier();
      __builtin_amdgcn_s_setprio(1);
#pragma unroll
      for (int ks = 0; ks < 2; ++ks)
#pragma unroll
        for (int r = 0; r < 4; ++r)
#pragma unroll
          for (int c = 0; c < 2; ++c)
            acc[mh * 4 + r][nh * 2 + c] = __builtin_amdgcn_mfma_f32_16x16x32_bf16(
                af[r][ks], bfv[c][ks], acc[mh * 4 + r][nh * 2 + c], 0, 0, 0);
      __builtin_amdgcn_s_setprio(0);
      if (q == 3 && k + 1 < nk) {
        if (k + 2 < nk) WAITV(4);
        else            WAITV(0);
      }
      __builtin_amdgcn_s_barrier();
    }
  }
#undef STG_A
#undef STG_B

  const int cr0 = (lane >> 4) * 4, cc = lane & 15;
#pragma unroll
  for (int mr = 0; mr < 8; ++mr)
#pragma unroll
    for (int nc = 0; nc < 4; ++nc)
#pragma unroll
      for (int j = 0; j < 4; ++j) {
        long row = bm + wm * 128 + mr * 16 + cr0 + j;
        long col = bn + wn * 64 + nc * 16 + cc;
        float v = acc[mr][nc][j] * scale;
        if (BIAS_MODE == 1) v += bias[z * bias_bs + col];
        else if (BIAS_MODE == 3)
          v += scale * (bias[row] * (b2[z * 768 + col] + 2048.0f * b4[col])
                        + b3[z * 768 + row] * b4[col]);
        long off = (long)z * c_bs + row * (long)ldc + col;
        if (OUT_BF16) ((unsigned short*)Cv)[off] = f2bf(v);
        else          ((float*)Cv)[off] = v;
      }
}

// -------- 256x128 half-N core, 2 phases/K-step, 3 buffers, depth-2 stage ----
template<int BIAS_MODE, int OUT_BF16>
__device__ __forceinline__ void gemm_hn_core(
    int z, long bm, long bn, unsigned short* __restrict__ lds,
    const unsigned short* __restrict__ A, const unsigned short* __restrict__ B,
    const float* __restrict__ bias, const float* __restrict__ b2,
    const float* __restrict__ b3, const float* __restrict__ b4,
    void* __restrict__ Cv,
    int K, int lda, int ldb, int ldc,
    long a_bs, long b_bs, long c_bs, long bias_bs, float scale)
{
  const int tid  = threadIdx.x;
  const int w    = tid >> 6;
  const int lane = tid & 63;
  const int wm   = w >> 2, wn = w & 3;
  const int fr   = lane & 15, kq = lane >> 4;
  const int srow = lane >> 3;
  const int schunk = (((lane & 7) ^ srow)) << 3;

  const unsigned short* Ab = A + (long)z * a_bs;
  const unsigned short* Bb = B + (long)z * b_bs;

  f32x4 acc[8][2];
#pragma unroll
  for (int r = 0; r < 8; ++r)
#pragma unroll
    for (int c = 0; c < 2; ++c) acc[r][c] = (f32x4){0.f, 0.f, 0.f, 0.f};

#define HSTG_A(p_, s_, k_) do { \
  _Pragma("unroll") for (int j_ = 0; j_ < 2; ++j_) { \
    const int idx_ = (w << 1) + j_; \
    const int grp_ = (idx_ < 8 ? idx_ : idx_ + 8) + (s_) * 8; \
    const unsigned short* g_ = Ab + (bm + grp_ * 8 + srow) * (long)lda + (k_) * 64 + schunk; \
    __builtin_amdgcn_global_load_lds((gmem_void*)g_, (lds_void*)(lds + (p_) * 24576 + grp_ * 512), 16, 0, 0); \
  } } while (0)
#define HSTG_B(p_, s_, k_) do { \
    const int grp_ = ((w >> 1) << 2) + (w & 1) + (s_) * 2; \
    const unsigned short* g_ = Bb + (bn + grp_ * 8 + srow) * (long)ldb + (k_) * 64 + schunk; \
    __builtin_amdgcn_global_load_lds((gmem_void*)g_, (lds_void*)(lds + (p_) * 24576 + 16384 + grp_ * 512), 16, 0, 0); \
  } while (0)

  const int nk = K / 64;   // >= 3 for all uses
  HSTG_A(0, 0, 0); HSTG_A(0, 1, 0); HSTG_B(0, 0, 0); HSTG_B(0, 1, 0);
  HSTG_A(1, 0, 1); HSTG_A(1, 1, 1); HSTG_B(1, 0, 1); HSTG_B(1, 1, 1);
  WAITV(6);
  __builtin_amdgcn_s_barrier();

  int pc = 0, pn2 = 2;
  for (int k = 0; k < nk; ++k) {
    short8 af[4][2], bfv[2][2];
#pragma unroll
    for (int r = 0; r < 4; ++r)
#pragma unroll
      for (int ks = 0; ks < 2; ++ks) {
        const int arow = wm * 128 + r * 16 + fr;
        af[r][ks] = *(const short8*)(lds + pc * 24576 + arow * 64 +
                                     ((((ks << 2) + kq) ^ (arow & 7)) << 3));
      }
#pragma unroll
    for (int c = 0; c < 2; ++c)
#pragma unroll
      for (int ks = 0; ks < 2; ++ks) {
        const int brow = wn * 32 + c * 16 + fr;
        bfv[c][ks] = *(const short8*)(lds + pc * 24576 + 16384 + brow * 64 +
                                      ((((ks << 2) + kq) ^ (brow & 7)) << 3));
      }
    if (k + 2 < nk) { HSTG_A(pn2, 0, k + 2); HSTG_B(pn2, 0, k + 2); }
    __builtin_amdgcn_s_barrier();
    __builtin_amdgcn_s_setprio(1);
#pragma unroll
    for (int ks = 0; ks < 2; ++ks)
#pragma unroll
      for (int r = 0; r < 4; ++r)
#pragma unroll
        for (int c = 0; c < 2; ++c)
          acc[r][c] = __builtin_amdgcn_mfma_f32_16x16x32_bf16(
              af[r][ks], bfv[c][ks], acc[r][c], 0, 0, 0);
    __builtin_amdgcn_s_setprio(0);
    __builtin_amdgcn_s_barrier();

#pragma unroll
    for (int r = 0; r < 4; ++r)
#pragma unroll
      for (int ks = 0; ks < 2; ++ks) {
        const int arow = wm * 128 + 64 + r * 16 + fr;
        af[r][ks] = *(const short8*)(lds + pc * 24576 + arow * 64 +
                                     ((((ks << 2) + kq) ^ (arow & 7)) << 3));
      }
    if (k + 2 < nk) { HSTG_A(pn2, 1, k + 2); HSTG_B(pn2, 1, k + 2); }
    __builtin_amdgcn_s_barrier();
    __builtin_amdgcn_s_setprio(1);
#pragma unroll
    for (int ks = 0; ks < 2; ++ks)
#pragma unroll
      for (int r = 0; r < 4; ++r)
#pragma unroll
        for (int c = 0; c < 2; ++c)
          acc[4 + r][c] = __builtin_amdgcn_mfma_f32_16x16x32_bf16(
              af[r][ks], bfv[c][ks], acc[4 + r][c], 0, 0, 0);
    __builtin_amdgcn_s_setprio(0);
    if (k + 1 < nk) {
      if (k + 2 < nk) WAITV(6);
      else            WAITV(0);
    }
    __builtin_amdgcn_s_barrier();

    pc  = (pc == 2)  ? 0 : pc + 1;
    pn2 = (pn2 == 2) ? 0 : pn2 + 1;
  }
#undef HSTG_A
#undef HSTG_B

  const int cr0 = (lane >> 4) * 4, cc = lane & 15;
#pragma unroll
  for (int mr = 0; mr < 8; ++mr)
#pragma unroll
    for (int nc = 0; nc < 2; ++nc)
#pragma unroll
      for (int j = 0; j < 4; ++j) {
        long row = bm + wm * 128 + mr * 16 + cr0 + j;
        long col = bn + wn * 32 + nc * 16 + cc;
        float v = acc[mr][nc][j] * scale;
        if (BIAS_MODE == 1) v += bias[z * bias_bs + col];
        else if (BIAS_MODE == 3)
          v += scale * (bias[row] * (b2[z * 768 + col] + 2048.0f * b4[col])
                        + b3[z * 768 + row] * b4[col]);
        long off = (long)z * c_bs + row * (long)ldc + col;
        if (OUT_BF16) ((unsigned short*)Cv)[off] = f2bf(v);
        else          ((float*)Cv)[off] = v;
      }
}

// -------- 256x192 core (final): 8 waves = 4M x 2N, 4 phases, 2 buffers ------
template<int BIAS_MODE, int OUT_BF16>
__device__ __forceinline__ void gemm_wn_core(
    int z, long bm, long bn, unsigned short* __restrict__ lds,
    const unsigned short* __restrict__ A, const unsigned short* __restrict__ B,
    const float* __restrict__ bias, void* __restrict__ Cv,
    int K, int lda, int ldb, int ldc,
    long a_bs, long b_bs, long c_bs, long bias_bs, float scale)
{
  const int tid  = threadIdx.x;
  const int w    = tid >> 6;
  const int lane = tid & 63;
  const int wm   = w >> 1, wn = w & 1;
  const int fr   = lane & 15, kq = lane >> 4;
  const int srow = lane >> 3;
  const int schunk = (((lane & 7) ^ srow)) << 3;

  const unsigned short* Ab = A + (long)z * a_bs;
  const unsigned short* Bb = B + (long)z * b_bs;

  f32x4 acc[4][6];
#pragma unroll
  for (int r = 0; r < 4; ++r)
#pragma unroll
    for (int c = 0; c < 6; ++c) acc[r][c] = (f32x4){0.f, 0.f, 0.f, 0.f};

#define WSTG_A(p_, s_, k_) do { \
  _Pragma("unroll") for (int j_ = 0; j_ < 2; ++j_) { \
    const int idx_ = (w << 1) + j_; \
    const int grp_ = (idx_ >> 2) * 8 + (idx_ & 3) + (s_) * 4; \
    const unsigned short* g_ = Ab + (bm + grp_ * 8 + srow) * (long)lda + (k_) * 64 + schunk; \
    __builtin_amdgcn_global_load_lds((gmem_void*)g_, (lds_void*)(lds + (p_) * 28672 + grp_ * 512), 16, 0, 0); \
  } } while (0)
#define WSTG_B(p_, s_, k_) do { \
  if (w < 4) { \
    _Pragma("unroll") for (int j_ = 0; j_ < 2; ++j_) { \
      const int idx_ = (w << 1) + j_; \
      const int grp_ = (idx_ < 6 ? idx_ : idx_ + 6) + (s_) * 6; \
      const unsigned short* g_ = Bb + (bn + grp_ * 8 + srow) * (long)ldb + (k_) * 64 + schunk; \
      __builtin_amdgcn_global_load_lds((gmem_void*)g_, (lds_void*)(lds + (p_) * 28672 + 16384 + grp_ * 512), 16, 0, 0); \
    } \
  } else { \
    const int idx_ = w + 4; \
    const int grp_ = (idx_ < 6 ? idx_ : idx_ + 6) + (s_) * 6; \
    const unsigned short* g_ = Bb + (bn + grp_ * 8 + srow) * (long)ldb + (k_) * 64 + schunk; \
    __builtin_amdgcn_global_load_lds((gmem_void*)g_, (lds_void*)(lds + (p_) * 28672 + 16384 + grp_ * 512), 16, 0, 0); \
  } } while (0)

  const int nk = K / 64;
  WSTG_A(0, 0, 0); WSTG_A(0, 1, 0); WSTG_B(0, 0, 0); WSTG_B(0, 1, 0);
  WSTG_A(1, 0, 1); WSTG_A(1, 1, 1); WSTG_B(1, 0, 1); WSTG_B(1, 1, 1);
  WAITV(6);
  __builtin_amdgcn_s_barrier();

  for (int k = 0; k < nk; ++k) {
    const int p = k & 1;
    short8 af[2][2], bf0[3][2], bf1[3][2];
#pragma unroll
    for (int r = 0; r < 2; ++r)
#pragma unroll
      for (int ks = 0; ks < 2; ++ks) {
        const int arow = wm * 64 + r * 16 + fr;
        af[r][ks] = *(const short8*)(lds + p * 28672 + arow * 64 +
                                     ((((ks << 2) + kq) ^ (arow & 7)) << 3));
      }
#pragma unroll
    for (int c = 0; c < 3; ++c)
#pragma unroll
      for (int ks = 0; ks < 2; ++ks) {
        const int brow = wn * 96 + c * 16 + fr;
        bf0[c][ks] = *(const short8*)(lds + p * 28672 + 16384 + brow * 64 +
                                      ((((ks << 2) + kq) ^ (brow & 7)) << 3));
      }
    if (k >= 1 && k + 1 < nk) WSTG_A((k + 1) & 1, 1, k + 1);
    __builtin_amdgcn_s_barrier();
    __builtin_amdgcn_s_setprio(1);
#pragma unroll
    for (int ks = 0; ks < 2; ++ks)
#pragma unroll
      for (int r = 0; r < 2; ++r)
#pragma unroll
        for (int c = 0; c < 3; ++c)
          acc[r][c] = __builtin_amdgcn_mfma_f32_16x16x32_bf16(
              af[r][ks], bf0[c][ks], acc[r][c], 0, 0, 0);
    __builtin_amdgcn_s_setprio(0);
    __builtin_amdgcn_s_barrier();

#pragma unroll
    for (int c = 0; c < 3; ++c)
#pragma unroll
      for (int ks = 0; ks < 2; ++ks) {
        const int brow = wn * 96 + 48 + c * 16 + fr;
        bf1[c][ks] = *(const short8*)(lds + p * 28672 + 16384 + brow * 64 +
                                      ((((ks << 2) + kq) ^ (brow & 7)) << 3));
      }
    if (k >= 1 && k + 1 < nk) WSTG_B((k + 1) & 1, 1, k + 1);
    __builtin_amdgcn_s_barrier();
    __builtin_amdgcn_s_setprio(1);
#pragma unroll
    for (int ks = 0; ks < 2; ++ks)
#pragma unroll
      for (int r = 0; r < 2; ++r)
#pragma unroll
        for (int c = 0; c < 3; ++c)
          acc[r][3 + c] = __builtin_amdgcn_mfma_f32_16x16x32_bf16(
              af[r][ks], bf1[c][ks], acc[r][3 + c], 0, 0, 0);
    __builtin_amdgcn_s_setprio(0);
    __builtin_amdgcn_s_barrier();

#pragma unroll
    for (int r = 0; r < 2; ++r)
#pragma unroll
      for (int ks = 0; ks < 2; ++ks) {
        const int arow = wm * 64 + 32 + r * 16 + fr;
        af[r][ks] = *(const short8*)(lds + p * 28672 + arow * 64 +
                                     ((((ks << 2) + kq) ^ (arow & 7)) << 3));
      }
    if (k + 2 < nk) WSTG_A(p, 0, k + 2);
    __builtin_amdgcn_s_barrier();
    __builtin_amdgcn_s_setprio(1);
#pragma unroll
    for (int ks = 0; ks < 2; ++ks)
#pragma unroll
      for (int r = 0; r < 2; ++r)
#pragma unroll
        for (int c = 0; c < 3; ++c)
          acc[2 + r][c] = __builtin_amdgcn_mfma_f32_16x16x32_bf16(
              af[r][ks], bf0[c][ks], acc[2 + r][c], 0, 0, 0);
    __builtin_amdgcn_s_setprio(0);
    __builtin_amdgcn_s_barrier();

    if (k + 2 < nk) WSTG_B(p, 0, k + 2);
    __builtin_amdgcn_s_barrier();
    __builtin_amdgcn_s_setprio(1);
#pragma unroll
    for (int ks = 0; ks < 2; ++ks)
#pragma unroll
      for (int r = 0; r < 2; ++r)
#pragma unroll
        for (int c = 0; c < 3; ++c)
          acc[2 + r][3 + c] = __builtin_amdgcn_mfma_f32_16x16x32_bf16(
              af[r][ks], bf1[c][ks], acc[2 + r][3 + c], 0, 0, 0);
    __builtin_amdgcn_s_setprio(0);
    if (k + 1 < nk) {
      if (k + 2 < nk) WAITV(3);
      else            WAITV(0);
    }
    __builtin_amdgcn_s_barrier();
  }
#undef WSTG_A
#undef WSTG_B

  const int cr0 = (lane >> 4) * 4, cc = lane & 15;
#pragma unroll
  for (int mr = 0; mr < 4; ++mr)
#pragma unroll
    for (int nc = 0; nc < 6; ++nc)
#pragma unroll
      for (int j = 0; j < 4; ++j) {
        long row = bm + wm * 64 + mr * 16 + cr0 + j;
        long col = bn + wn * 96 + nc * 16 + cc;
        float v = acc[mr][nc][j] * scale;
        if (BIAS_MODE == 1) v += bias[z * bias_bs + col];
        long off = (long)z * c_bs + row * (long)ldc + col;
        if (OUT_BF16) ((unsigned short*)Cv)[off] = f2bf(v);
        else          ((float*)Cv)[off] = v;
      }
}

// ---- launch 2: G split-K x2 upper-tri (0..191) + F (192..200) + c1,a2 (201..224) + s (225..232)
// Gpart: [(z*12+tile)*2+s][256][128] f32.  Tiles: t<6 -> (0,t); t<10 -> (1,t-4); else (2,t-6).
__global__ __launch_bounds__(512, 1) void gsf_k(
    const unsigned short* xt, float* Gpart,
    const unsigned short* wqtb, const unsigned short* wktb, unsigned short* F,
    const float* bq, const float* bk, const float* partials,
    float* c1v, float* a2v, float* sv)
{
  __shared__ unsigned short lds[73728];
  const int bid = blockIdx.x, tid = threadIdx.x;
  if (bid < 192) {
    const int z = bid & 7, rem = bid >> 3;   // rem 0..23
    const int tile = rem >> 1, s = rem & 1;
    int ti, tj;
    if (tile < 6)       { ti = 0; tj = tile; }
    else if (tile < 10) { ti = 1; tj = tile - 4; }
    else                { ti = 2; tj = tile - 6; }
    const long bm = (long)ti * 256, bn = (long)tj * 128;
    float* Cv = Gpart + ((long)(z * 12 + tile) * 2 + s) * 32768 - (bm * 128 + bn);
    gemm_hn_core<0, 0>(z, bm, bn, lds,
        xt + s * 1024, xt + s * 1024, nullptr, nullptr, nullptr, nullptr, Cv,
        1024, 2048, 2048, 128, 768L * 2048, 768L * 2048, 0, 0, 1.0f);
  } else if (bid < 201) {                 // F = wqt · wkt^T, 3x3 256^2 tiles
    const int t = bid - 192;
    gemm256_core<0, 1>(0, (long)(t / 3) * 256, (long)(t % 3) * 256, lds,
        wqtb, wktb, nullptr, nullptr, nullptr, nullptr, F,
        768, 768, 768, 768, 0, 0, 0, 0, 1.0f);
  } else if (bid < 225) {                 // c1[r]=wkt[r,:]·bq ; a2[r]=wqt[r,:]·bk
    const int wid = tid >> 6, lane = tid & 63;
    const int r0 = (bid - 201) * 32;
#pragma unroll
    for (int mi = 0; mi < 4; ++mi) {
      const int r = r0 + wid * 4 + mi;
      const unsigned short* rk = wktb + (long)r * 768;
      const unsigned short* rq = wqtb + (long)r * 768;
      float ac = 0.f, aa = 0.f;
#pragma unroll
      for (int i = 0; i < 12; ++i) {
        const int k = lane + i * 64;
        ac += bf2f(rk[k]) * bq[k];
        aa += bf2f(rq[k]) * bk[k];
      }
      ac = wave_red(ac); aa = wave_red(aa);
      if (lane == 0) { c1v[r] = ac; a2v[r] = aa; }
    }
  } else {                                // s[z,d] from colsum partials
    const int z = bid - 225;
    for (int d = tid; d < 768; d += 512) {
      const float* pp = partials + ((long)z * 768 + d) * 32;
      float s = 0.f;
#pragma unroll
      for (int j = 0; j < 32; ++j) s += pp[j];
      sv[z * 768 + d] = s;
    }
  }
}

// ---- launch 3: G reduce + mirror. 768 blocks x 256 thr, one 64x64 region ---
__global__ __launch_bounds__(256) void gred_k(
    const float* __restrict__ Gpart, unsigned short* __restrict__ G)
{
  __shared__ unsigned short ldsT[64][72];
  const int bid = blockIdx.x, tid = threadIdx.x;
  const int unit = bid >> 3;              // 0..95 = z*12+tile
  const int reg  = bid & 7;
  const int z = unit / 12, tile = unit % 12;
  int ti, tj;
  if (tile < 6)       { ti = 0; tj = tile; }
  else if (tile < 10) { ti = 1; tj = tile - 4; }
  else                { ti = 2; tj = tile - 6; }
  const bool mir = (tj >= 2 * ti + 2);    // fully above diagonal
  const int rr = reg >> 1, rc = reg & 1;  // 4x2 regions of 64x64
  const int row = tid >> 2;               // 0..63
  const int cb  = (tid & 3) * 16;
  const float* p0 = Gpart + ((long)unit * 2 + 0) * 32768 + (long)(rr * 64 + row) * 128 + rc * 64 + cb;
  const float* p1 = Gpart + ((long)unit * 2 + 1) * 32768 + (long)(rr * 64 + row) * 128 + rc * 64 + cb;
  float accv[16];
#pragma unroll
  for (int i = 0; i < 4; ++i) {
    float4 a = *(const float4*)(p0 + i * 4);
    float4 b = *(const float4*)(p1 + i * 4);
    accv[i * 4 + 0] = a.x + b.x; accv[i * 4 + 1] = a.y + b.y;
    accv[i * 4 + 2] = a.z + b.z; accv[i * 4 + 3] = a.w + b.w;
  }
  unsigned short ob[16];
#pragma unroll
  for (int i = 0; i < 16; ++i) ob[i] = f2bf(accv[i]);
  unsigned short* gd = G + (long)z * 589824
                     + (long)(ti * 256 + rr * 64 + row) * 768 + tj * 128 + rc * 64 + cb;
  *(ushort8*)gd = *(ushort8*)ob;
  *(ushort8*)(gd + 8) = *(ushort8*)(ob + 8);
  if (mir) {
#pragma unroll
    for (int i = 0; i < 16; ++i) ldsT[cb + i][row] = ob[i];
    __syncthreads();
    unsigned short* gm = G + (long)z * 589824
                       + (long)(tj * 128 + rc * 64 + row) * 768 + ti * 256 + rr * 64 + cb;
    unsigned short mb[16];
#pragma unroll
    for (int i = 0; i < 16; ++i) mb[i] = ldsT[row][cb + i];
    *(ushort8*)gm = *(ushort8*)mb;
    *(ushort8*)(gm + 8) = *(ushort8*)(mb + 8);
  }
}

// ---- launch 4: a1/w/g GEMVs — 576 blocks x 256 thr, no LDS -----------------
__global__ __launch_bounds__(256) void vec_k(
    const unsigned short* __restrict__ Fb, const unsigned short* __restrict__ G,
    const float* __restrict__ Wv, const float* __restrict__ sv,
    const float* __restrict__ c1v,
    float* __restrict__ a1v, float* __restrict__ wvv, float* __restrict__ gv)
{
  const int bid = blockIdx.x, tid = threadIdx.x;
  const int type = bid / 192, u = bid % 192;
  const int z = u / 24, r0 = (u % 24) * 32;
  const int wid = tid >> 6, lane = tid & 63;
#pragma unroll
  for (int mi = 0; mi < 8; ++mi) {
    const int r = r0 + wid * 8 + mi;
    float a = 0.f;
    if (type == 0) {                      // a1[z,r] = F[r,:]·s[z,:]
      const unsigned short* row = Fb + (long)r * 768;
      const float* vec = sv + z * 768;
#pragma unroll
      for (int i = 0; i < 12; ++i) {
        const int k = lane + i * 64;
        a += bf2f(row[k]) * vec[k];
      }
    } else if (type == 1) {               // w[z,r] = Wv[r,:]·s[z,:]
      const float* row = Wv + (long)r * 768;
      const float* vec = sv + z * 768;
#pragma unroll
      for (int i = 0; i < 12; ++i) {
        const int k = lane + i * 64;
        a += row[k] * vec[k];
      }
    } else {                              // g[z,r] = G[z][r,:]·c1
      const unsigned short* row = G + (long)z * 589824 + (long)r * 768;
#pragma unroll
      for (int i = 0; i < 12; ++i) {
        const int k = lane + i * 64;
        a += bf2f(row[k]) * c1v[k];
      }
    }
    a = wave_red(a);
    if (lane == 0) {
      if (type == 0) a1v[z * 768 + r] = a;
      else if (type == 1) wvv[z * 768 + r] = a;
      else gv[z * 768 + r] = a;
    }
  }
}

// ---- launch 5: H = F·G 256x128 (144 blocks) --------------------------------
__global__ __launch_bounds__(512, 1) void hv_k(
    const unsigned short* Fb, const unsigned short* G, unsigned short* H)
{
  __shared__ unsigned short lds[73728];
  const int z = blockIdx.x & 7, t = blockIdx.x >> 3;
  gemm_hn_core<0, 1>(z, (long)(t / 6) * 256, (long)(t % 6) * 128, lds,
      Fb, G, nullptr, nullptr, nullptr, nullptr, H,
      768, 768, 768, 768, 0, 768L * 768, 768L * 768, 0, 1.0f);
}

// ---- launch 6: Pt 256x128 (0..143) + r blocks (144..335) -------------------
__global__ __launch_bounds__(512, 1) void pt_k(
    const unsigned short* wvb, const unsigned short* H, unsigned short* Pt,
    const float* bv, const float* a1v, const float* wvv, const float* a2v,
    const float* Wv, const float* gv, const float* c1v, const float* sv,
    const float* bq, const float* bk, float* rv)
{
  __shared__ unsigned short lds[73728];
  const float inv_sqrt_d = 0.036084391824351615f;
  const int bid = blockIdx.x, tid = threadIdx.x;
  if (bid < 144) {
    const int z = bid & 7, t = bid >> 3;
    gemm_hn_core<3, 1>(z, (long)(t / 6) * 256, (long)(t % 6) * 128, lds,
        wvb, H, bv, a1v, wvv, a2v, Pt,
        768, 768, 768, 768, 0, 768L * 768, 768L * 768, 0, inv_sqrt_d);
  } else {
    float* red1 = (float*)lds;
    float* red2 = red1 + 512;
    const int u = bid - 144;
    const int z = u / 24, r0 = (u % 24) * 32;
    const int wid = tid >> 6, lane = tid & 63;
    float p1 = 0.f, p2 = 0.f;
    for (int d = tid; d < 768; d += 512) {
      p1 += c1v[d] * sv[z * 768 + d];
      p2 += bq[d] * bk[d];
    }
    red1[tid] = p1; red2[tid] = p2;
    __syncthreads();
    for (int st = 256; st > 0; st >>= 1) {
      if (tid < st) { red1[tid] += red1[tid + st]; red2[tid] += red2[tid + st]; }
      __syncthreads();
    }
    const float cs = red1[0], bb = red2[0];
#pragma unroll
    for (int mi = 0; mi < 4; ++mi) {
      const int o = r0 + wid * 4 + mi;
      const float* row = Wv + (long)o * 768;
      const float* vec = gv + z * 768;
      float a = 0.f;
#pragma unroll
      for (int i = 0; i < 12; ++i) {
        const int k = lane + i * 64;
        a += row[k] * vec[k];
      }
      a = wave_red(a);
      if (lane == 0)
        rv[z * 768 + o] = inv_sqrt_d *
            (a + cs * bv[o] + bb * (wvv[z * 768 + o] + 2048.0f * bv[o]));
    }
  }
}

// ---- launch 7: out = xb·Pt^T + r   (256x192 core, 256 blocks) --------------
__global__ __launch_bounds__(512, 1) void final_k(
    const unsigned short* xb, const unsigned short* Pt, const float* rv, float* out)
{
  __shared__ unsigned short lds[57344];
  const int z = blockIdx.x & 7, t = blockIdx.x >> 3;
  gemm_wn_core<1, 0>(z, (long)(t >> 2) * 256, (long)(t & 3) * 192, lds,
      xb, Pt, rv, out,
      768, 768, 768, 768, 2048L * 768, 768L * 768, 2048L * 768, 768, 1.0f);
}

extern "C" void kernel_launch(void* const* d_in, const int* in_sizes, int n_in,
                              void* d_out, int out_size, void* d_ws, size_t ws_size,
                              hipStream_t stream) {
  const float* x  = (const float*)d_in[0];
  const float* Wq = (const float*)d_in[1];
  const float* bq = (const float*)d_in[2];
  const float* Wk = (const float*)d_in[3];
  const float* bk = (const float*)d_in[4];
  const float* Wv = (const float*)d_in[5];
  const float* bv = (const float*)d_in[6];
  float* out = (float*)d_out;

  const int Bsz = 8, L = 2048, D = 768;
  const long xN = (long)Bsz * L * D;
  const long wN = (long)D * D;
  const long D2 = wN;

  char* ws = (char*)d_ws;
  unsigned short* xt   = (unsigned short*)ws; ws += xN * 2;
  unsigned short* xb   = (unsigned short*)ws; ws += xN * 2;
  unsigned short* wqtb = (unsigned short*)ws; ws += wN * 2;
  unsigned short* wktb = (unsigned short*)ws; ws += wN * 2;
  unsigned short* wvb  = (unsigned short*)ws; ws += wN * 2;
  unsigned short* Fb   = (unsigned short*)ws; ws += wN * 2;
  unsigned short* regA = (unsigned short*)ws; ws += (long)Bsz * D2 * 2;  // G, later Pt
  unsigned short* regB = (unsigned short*)ws; ws += (long)Bsz * D2 * 2;  // H
  float* Gpart = (float*)ws; ws += 96L * 2 * 32768 * 4;                  // 25.2 MB
  float* partials = (float*)ws; ws += (long)Bsz * D * 32 * 4;
  float* sv  = (float*)ws; ws += (long)Bsz * D * 4;
  float* c1v = (float*)ws; ws += (long)D * 4;
  float* a2v = (float*)ws; ws += (long)D * 4;
  float* a1v = (float*)ws; ws += (long)Bsz * D * 4;
  float* wvv = (float*)ws; ws += (long)Bsz * D * 4;
  float* gv  = (float*)ws; ws += (long)Bsz * D * 4;
  float* rv  = (float*)ws; ws += (long)Bsz * D * 4;

  preamble<<<dim3(4512), dim3(256), 0, stream>>>(x, Wq, Wk, Wv, xb, xt, wqtb, wktb, wvb, partials);

  gsf_k<<<dim3(233), dim3(512), 0, stream>>>(xt, Gpart, wqtb, wktb, Fb,
                                             bq, bk, partials, c1v, a2v, sv);

  gred_k<<<dim3(768), dim3(256), 0, stream>>>(Gpart, regA);

  vec_k<<<dim3(576), dim3(256), 0, stream>>>(Fb, regA, Wv, sv, c1v, a1v, wvv, gv);

  hv_k<<<dim3(144), dim3(512), 0, stream>>>(Fb, regA, regB);

  pt_k<<<dim3(336), dim3(512), 0, stream>>>(wvb, regB, regA, bv, a1v, wvv, a2v,
                                            Wv, gv, c1v, sv, bq, bk, rv);

  final_k<<<dim3(256), dim3(512), 0, stream>>>(xb, regA, rv, out);

  (void)in_sizes; (void)n_in; (void)out_size; (void)ws_size;
}

// Round 18
// 117.651 us; speedup vs baseline: 1.0190x; 1.0190x over previous
//
#include <hip/hip_runtime.h>
#include <hip/hip_bf16.h>
#include <stdint.h>

// out = (QK^T/sqrt(d))V = Q (K^T V)/sqrt(d)   (no softmax in ref)
// F = Wq^T Wk;  G = x^T x;  H = F G;
// Pt = [Wv H^T + bv a1^T + w a2^T + L bv a2^T]/sqrt(d)
// r[z,o] = [Wv·g + cs bv + bb (w + L bv)]/sqrt(d);  out = xb Pt^T + 1 r^T
// Round-18: REVERT to round-16 config (best measured, 117.9us). Round-17's
// split-K G + gred was a measured regression (+2us: extra launch + 25MB f32
// partial traffic outweighed the shorter G wall).

typedef __attribute__((ext_vector_type(8))) short short8;
typedef __attribute__((ext_vector_type(8))) unsigned short ushort8;
typedef __attribute__((ext_vector_type(4))) float f32x4;
typedef __attribute__((address_space(3))) void lds_void;
typedef const __attribute__((address_space(1))) void gmem_void;

#define WAITV(n) asm volatile("s_waitcnt vmcnt(" #n ")" ::: "memory")

__device__ __forceinline__ unsigned short f2bf(float f) {
  union { float f; unsigned u; } v; v.f = f;
  unsigned r = v.u + 0x7fff + ((v.u >> 16) & 1);   // RNE
  return (unsigned short)(r >> 16);
}
__device__ __forceinline__ float bf2f(unsigned short u) {
  union { unsigned u; float f; } v; v.u = ((unsigned)u) << 16; return v.f;
}
__device__ __forceinline__ float wave_red(float a) {
#pragma unroll
  for (int off = 32; off; off >>= 1) a += __shfl_down(a, off);
  return a;
}

// ---------------- preamble: x->xt,xb,col-partials; Wq^T,Wk^T,Wv casts -------
__global__ __launch_bounds__(256) void preamble(
    const float* __restrict__ x, const float* __restrict__ Wq,
    const float* __restrict__ Wk, const float* __restrict__ Wv,
    unsigned short* __restrict__ xb, unsigned short* __restrict__ xt,
    unsigned short* __restrict__ wqtb, unsigned short* __restrict__ wktb,
    unsigned short* __restrict__ wvb, float* __restrict__ partials)
{
  const int bid = blockIdx.x;
  const int tid = threadIdx.x;
  if (bid < 3072) {                       // x role: 64l x 64d tile
    __shared__ float tile[64][65];
    __shared__ float pt4[4][64];
    const int z = bid / 384, rem = bid % 384;
    const int l0 = (rem / 12) * 64, d0 = (rem % 12) * 64;
    const int tx = tid & 63, ty = tid >> 6;          // ty 0..3
    const float* xz = x + ((long)z * 2048 + l0) * 768 + d0;
    float colacc = 0.f;
#pragma unroll
    for (int i = 0; i < 16; ++i) {
      const int l = i * 4 + ty;
      float v = xz[(long)l * 768 + tx];
      tile[l][tx] = v;
      colacc += v;
    }
    pt4[ty][tx] = colacc;
    __syncthreads();
    if (ty == 0)
      partials[((long)z * 768 + d0 + tx) * 32 + (l0 >> 6)] =
          pt4[0][tx] + pt4[1][tx] + pt4[2][tx] + pt4[3][tx];
    unsigned short* xbz = xb + ((long)z * 2048 + l0) * 768 + d0;
    const int jr = tid & 7, rw = tid >> 3;           // rw 0..31
#pragma unroll
    for (int it = 0; it < 2; ++it) {
      const int row = it * 32 + rw;
      unsigned short o[8];
#pragma unroll
      for (int e = 0; e < 8; ++e) o[e] = f2bf(tile[row][jr * 8 + e]);
      *(ushort8*)(xbz + (long)row * 768 + jr * 8) = *(ushort8*)o;
    }
    unsigned short* xtz = xt + ((long)z * 768 + d0) * 2048 + l0;
#pragma unroll
    for (int it = 0; it < 2; ++it) {
      const int d = it * 32 + rw;
      unsigned short o[8];
#pragma unroll
      for (int e = 0; e < 8; ++e) o[e] = f2bf(tile[jr * 8 + e][d]);
      *(ushort8*)(xtz + (long)d * 2048 + jr * 8) = *(ushort8*)o;
    }
  } else if (bid < 4224) {                // weight transpose (wq, wk)
    __shared__ float tl[32][33];
    int t = bid - 3072;
    const float* W = (t < 576) ? Wq : Wk;
    unsigned short* O = (t < 576) ? wqtb : wktb;
    t = (t >= 576) ? t - 576 : t;
    const int r0 = (t / 24) * 32, c0 = (t % 24) * 32;
    const int tx = tid & 31, ty = tid >> 5;
    for (int i = ty; i < 32; i += 8) tl[i][tx] = W[(long)(r0 + i) * 768 + c0 + tx];
    __syncthreads();
    for (int i = ty; i < 32; i += 8) O[(long)(c0 + i) * 768 + r0 + tx] = f2bf(tl[tx][i]);
  } else {                                // wv cast, 288 blocks x 2048 elems
    const int t = bid - 4224;
    const long i = ((long)t * 256 + tid) * 8;
    float4 v0 = *(const float4*)(Wv + i);
    float4 v1 = *(const float4*)(Wv + i + 4);
    unsigned short o[8];
    o[0] = f2bf(v0.x); o[1] = f2bf(v0.y); o[2] = f2bf(v0.z); o[3] = f2bf(v0.w);
    o[4] = f2bf(v1.x); o[5] = f2bf(v1.y); o[6] = f2bf(v1.z); o[7] = f2bf(v1.w);
    *(ushort8*)(wvb + i) = *(ushort8*)o;
  }
}

// -------- 256^2 8-phase counted-vmcnt core (T3+T4).  512 thr, 8 waves ------
template<int BIAS_MODE, int OUT_BF16>
__device__ __forceinline__ void gemm256_core(
    int z, long bm, long bn, unsigned short* __restrict__ lds,
    const unsigned short* __restrict__ A, const unsigned short* __restrict__ B,
    const float* __restrict__ bias, const float* __restrict__ b2,
    const float* __restrict__ b3, const float* __restrict__ b4,
    void* __restrict__ Cv,
    int K, int lda, int ldb, int ldc,
    long a_bs, long b_bs, long c_bs, long bias_bs, float scale)
{
  const int tid  = threadIdx.x;
  const int w    = tid >> 6;
  const int lane = tid & 63;
  const int wm   = w >> 2, wn = w & 3;
  const int fr   = lane & 15, kq = lane >> 4;
  const int srow = lane >> 3;
  const int schunk = (((lane & 7) ^ srow)) << 3;

  const unsigned short* Ab = A + (long)z * a_bs;
  const unsigned short* Bb = B + (long)z * b_bs;

  f32x4 acc[8][4];
#pragma unroll
  for (int r = 0; r < 8; ++r)
#pragma unroll
    for (int c = 0; c < 4; ++c) acc[r][c] = (f32x4){0.f, 0.f, 0.f, 0.f};

#define STG_A(p_, s_, k_) do { \
  _Pragma("unroll") for (int j_ = 0; j_ < 2; ++j_) { \
    const int idx_ = (w << 1) + j_; \
    const int grp_ = (idx_ < 8 ? idx_ : idx_ + 8) + (s_) * 8; \
    const unsigned short* g_ = Ab + (bm + grp_ * 8 + srow) * (long)lda + (k_) * 64 + schunk; \
    __builtin_amdgcn_global_load_lds((gmem_void*)g_, (lds_void*)(lds + (p_) * 32768 + grp_ * 512), 16, 0, 0); \
  } } while (0)
#define STG_B(p_, s_, k_) do { \
  _Pragma("unroll") for (int j_ = 0; j_ < 2; ++j_) { \
    const int idx_ = (w << 1) + j_; \
    const int grp_ = ((idx_ >> 2) << 3) + (idx_ & 3) + (s_) * 4; \
    const unsigned short* g_ = Bb + (bn + grp_ * 8 + srow) * (long)ldb + (k_) * 64 + schunk; \
    __builtin_amdgcn_global_load_lds((gmem_void*)g_, (lds_void*)(lds + (p_) * 32768 + 16384 + grp_ * 512), 16, 0, 0); \
  } } while (0)

  const int nk = K / 64;
  STG_A(0, 0, 0); STG_A(0, 1, 0); STG_B(0, 0, 0); STG_B(0, 1, 0);
  STG_A(1, 0, 1); STG_A(1, 1, 1); STG_B(1, 0, 1); STG_B(1, 1, 1);
  WAITV(8);
  __builtin_amdgcn_s_barrier();

  for (int k = 0; k < nk; ++k) {
    const int p = k & 1;
#pragma unroll
    for (int q = 0; q < 4; ++q) {
      const int mh = q >> 1, nh = q & 1;
      short8 af[4][2], bfv[2][2];
#pragma unroll
      for (int r = 0; r < 4; ++r)
#pragma unroll
        for (int ks = 0; ks < 2; ++ks) {
          const int arow = wm * 128 + mh * 64 + r * 16 + fr;
          af[r][ks] = *(const short8*)(lds + p * 32768 + arow * 64 +
                                       ((((ks << 2) + kq) ^ (arow & 7)) << 3));
        }
#pragma unroll
      for (int c = 0; c < 2; ++c)
#pragma unroll
        for (int ks = 0; ks < 2; ++ks) {
          const int brow = wn * 64 + nh * 32 + c * 16 + fr;
          bfv[c][ks] = *(const short8*)(lds + p * 32768 + 16384 + brow * 64 +
                                        ((((ks << 2) + kq) ^ (brow & 7)) << 3));
        }
      if (q == 0)      { if (k >= 1 && k + 1 < nk) STG_A((k + 1) & 1, 1, k + 1); }
      else if (q == 1) { if (k >= 1 && k + 1 < nk) STG_B((k + 1) & 1, 1, k + 1); }
      else if (q == 2) { if (k + 2 < nk) STG_A(p, 0, k + 2); }
      else             { if (k + 2 < nk) STG_B(p, 0, k + 2); }

      __builtin_amdgcn_s_barrier();
      __builtin_amdgcn_s_setprio(1);
#pragma unroll
      for (int ks = 0; ks < 2; ++ks)
#pragma unroll
        for (int r = 0; r < 4; ++r)
#pragma unroll
          for (int c = 0; c < 2; ++c)
            acc[mh * 4 + r][nh * 2 + c] = __builtin_amdgcn_mfma_f32_16x16x32_bf16(
                af[r][ks], bfv[c][ks], acc[mh * 4 + r][nh * 2 + c], 0, 0, 0);
      __builtin_amdgcn_s_setprio(0);
      if (q == 3 && k + 1 < nk) {
        if (k + 2 < nk) WAITV(4);
        else            WAITV(0);
      }
      __builtin_amdgcn_s_barrier();
    }
  }
#undef STG_A
#undef STG_B

  const int cr0 = (lane >> 4) * 4, cc = lane & 15;
#pragma unroll
  for (int mr = 0; mr < 8; ++mr)
#pragma unroll
    for (int nc = 0; nc < 4; ++nc)
#pragma unroll
      for (int j = 0; j < 4; ++j) {
        long row = bm + wm * 128 + mr * 16 + cr0 + j;
        long col = bn + wn * 64 + nc * 16 + cc;
        float v = acc[mr][nc][j] * scale;
        if (BIAS_MODE == 1) v += bias[z * bias_bs + col];
        else if (BIAS_MODE == 3)
          v += scale * (bias[row] * (b2[z * 768 + col] + 2048.0f * b4[col])
                        + b3[z * 768 + row] * b4[col]);
        long off = (long)z * c_bs + row * (long)ldc + col;
        if (OUT_BF16) ((unsigned short*)Cv)[off] = f2bf(v);
        else          ((float*)Cv)[off] = v;
      }
}

// -------- 256x128 half-N core, 2 phases/K-step, 3 buffers, depth-2 stage ----
template<int BIAS_MODE, int OUT_BF16>
__device__ __forceinline__ void gemm_hn_core(
    int z, long bm, long bn, unsigned short* __restrict__ lds,
    const unsigned short* __restrict__ A, const unsigned short* __restrict__ B,
    const float* __restrict__ bias, const float* __restrict__ b2,
    const float* __restrict__ b3, const float* __restrict__ b4,
    void* __restrict__ Cv,
    int K, int lda, int ldb, int ldc,
    long a_bs, long b_bs, long c_bs, long bias_bs, float scale)
{
  const int tid  = threadIdx.x;
  const int w    = tid >> 6;
  const int lane = tid & 63;
  const int wm   = w >> 2, wn = w & 3;
  const int fr   = lane & 15, kq = lane >> 4;
  const int srow = lane >> 3;
  const int schunk = (((lane & 7) ^ srow)) << 3;

  const unsigned short* Ab = A + (long)z * a_bs;
  const unsigned short* Bb = B + (long)z * b_bs;

  f32x4 acc[8][2];
#pragma unroll
  for (int r = 0; r < 8; ++r)
#pragma unroll
    for (int c = 0; c < 2; ++c) acc[r][c] = (f32x4){0.f, 0.f, 0.f, 0.f};

#define HSTG_A(p_, s_, k_) do { \
  _Pragma("unroll") for (int j_ = 0; j_ < 2; ++j_) { \
    const int idx_ = (w << 1) + j_; \
    const int grp_ = (idx_ < 8 ? idx_ : idx_ + 8) + (s_) * 8; \
    const unsigned short* g_ = Ab + (bm + grp_ * 8 + srow) * (long)lda + (k_) * 64 + schunk; \
    __builtin_amdgcn_global_load_lds((gmem_void*)g_, (lds_void*)(lds + (p_) * 24576 + grp_ * 512), 16, 0, 0); \
  } } while (0)
#define HSTG_B(p_, s_, k_) do { \
    const int grp_ = ((w >> 1) << 2) + (w & 1) + (s_) * 2; \
    const unsigned short* g_ = Bb + (bn + grp_ * 8 + srow) * (long)ldb + (k_) * 64 + schunk; \
    __builtin_amdgcn_global_load_lds((gmem_void*)g_, (lds_void*)(lds + (p_) * 24576 + 16384 + grp_ * 512), 16, 0, 0); \
  } while (0)

  const int nk = K / 64;   // >= 3 for all uses
  HSTG_A(0, 0, 0); HSTG_A(0, 1, 0); HSTG_B(0, 0, 0); HSTG_B(0, 1, 0);
  HSTG_A(1, 0, 1); HSTG_A(1, 1, 1); HSTG_B(1, 0, 1); HSTG_B(1, 1, 1);
  WAITV(6);
  __builtin_amdgcn_s_barrier();

  int pc = 0, pn2 = 2;
  for (int k = 0; k < nk; ++k) {
    short8 af[4][2], bfv[2][2];
#pragma unroll
    for (int r = 0; r < 4; ++r)
#pragma unroll
      for (int ks = 0; ks < 2; ++ks) {
        const int arow = wm * 128 + r * 16 + fr;
        af[r][ks] = *(const short8*)(lds + pc * 24576 + arow * 64 +
                                     ((((ks << 2) + kq) ^ (arow & 7)) << 3));
      }
#pragma unroll
    for (int c = 0; c < 2; ++c)
#pragma unroll
      for (int ks = 0; ks < 2; ++ks) {
        const int brow = wn * 32 + c * 16 + fr;
        bfv[c][ks] = *(const short8*)(lds + pc * 24576 + 16384 + brow * 64 +
                                      ((((ks << 2) + kq) ^ (brow & 7)) << 3));
      }
    if (k + 2 < nk) { HSTG_A(pn2, 0, k + 2); HSTG_B(pn2, 0, k + 2); }
    __builtin_amdgcn_s_barrier();
    __builtin_amdgcn_s_setprio(1);
#pragma unroll
    for (int ks = 0; ks < 2; ++ks)
#pragma unroll
      for (int r = 0; r < 4; ++r)
#pragma unroll
        for (int c = 0; c < 2; ++c)
          acc[r][c] = __builtin_amdgcn_mfma_f32_16x16x32_bf16(
              af[r][ks], bfv[c][ks], acc[r][c], 0, 0, 0);
    __builtin_amdgcn_s_setprio(0);
    __builtin_amdgcn_s_barrier();

#pragma unroll
    for (int r = 0; r < 4; ++r)
#pragma unroll
      for (int ks = 0; ks < 2; ++ks) {
        const int arow = wm * 128 + 64 + r * 16 + fr;
        af[r][ks] = *(const short8*)(lds + pc * 24576 + arow * 64 +
                                     ((((ks << 2) + kq) ^ (arow & 7)) << 3));
      }
    if (k + 2 < nk) { HSTG_A(pn2, 1, k + 2); HSTG_B(pn2, 1, k + 2); }
    __builtin_amdgcn_s_barrier();
    __builtin_amdgcn_s_setprio(1);
#pragma unroll
    for (int ks = 0; ks < 2; ++ks)
#pragma unroll
      for (int r = 0; r < 4; ++r)
#pragma unroll
        for (int c = 0; c < 2; ++c)
          acc[4 + r][c] = __builtin_amdgcn_mfma_f32_16x16x32_bf16(
              af[r][ks], bfv[c][ks], acc[4 + r][c], 0, 0, 0);
    __builtin_amdgcn_s_setprio(0);
    if (k + 1 < nk) {
      if (k + 2 < nk) WAITV(6);
      else            WAITV(0);
    }
    __builtin_amdgcn_s_barrier();

    pc  = (pc == 2)  ? 0 : pc + 1;
    pn2 = (pn2 == 2) ? 0 : pn2 + 1;
  }
#undef HSTG_A
#undef HSTG_B

  const int cr0 = (lane >> 4) * 4, cc = lane & 15;
#pragma unroll
  for (int mr = 0; mr < 8; ++mr)
#pragma unroll
    for (int nc = 0; nc < 2; ++nc)
#pragma unroll
      for (int j = 0; j < 4; ++j) {
        long row = bm + wm * 128 + mr * 16 + cr0 + j;
        long col = bn + wn * 32 + nc * 16 + cc;
        float v = acc[mr][nc][j] * scale;
        if (BIAS_MODE == 1) v += bias[z * bias_bs + col];
        else if (BIAS_MODE == 3)
          v += scale * (bias[row] * (b2[z * 768 + col] + 2048.0f * b4[col])
                        + b3[z * 768 + row] * b4[col]);
        long off = (long)z * c_bs + row * (long)ldc + col;
        if (OUT_BF16) ((unsigned short*)Cv)[off] = f2bf(v);
        else          ((float*)Cv)[off] = v;
      }
}

// -------- 256x192 core (final): 8 waves = 4M x 2N, 4 phases, 2 buffers ------
template<int BIAS_MODE, int OUT_BF16>
__device__ __forceinline__ void gemm_wn_core(
    int z, long bm, long bn, unsigned short* __restrict__ lds,
    const unsigned short* __restrict__ A, const unsigned short* __restrict__ B,
    const float* __restrict__ bias, void* __restrict__ Cv,
    int K, int lda, int ldb, int ldc,
    long a_bs, long b_bs, long c_bs, long bias_bs, float scale)
{
  const int tid  = threadIdx.x;
  const int w    = tid >> 6;
  const int lane = tid & 63;
  const int wm   = w >> 1, wn = w & 1;
  const int fr   = lane & 15, kq = lane >> 4;
  const int srow = lane >> 3;
  const int schunk = (((lane & 7) ^ srow)) << 3;

  const unsigned short* Ab = A + (long)z * a_bs;
  const unsigned short* Bb = B + (long)z * b_bs;

  f32x4 acc[4][6];
#pragma unroll
  for (int r = 0; r < 4; ++r)
#pragma unroll
    for (int c = 0; c < 6; ++c) acc[r][c] = (f32x4){0.f, 0.f, 0.f, 0.f};

#define WSTG_A(p_, s_, k_) do { \
  _Pragma("unroll") for (int j_ = 0; j_ < 2; ++j_) { \
    const int idx_ = (w << 1) + j_; \
    const int grp_ = (idx_ >> 2) * 8 + (idx_ & 3) + (s_) * 4; \
    const unsigned short* g_ = Ab + (bm + grp_ * 8 + srow) * (long)lda + (k_) * 64 + schunk; \
    __builtin_amdgcn_global_load_lds((gmem_void*)g_, (lds_void*)(lds + (p_) * 28672 + grp_ * 512), 16, 0, 0); \
  } } while (0)
#define WSTG_B(p_, s_, k_) do { \
  if (w < 4) { \
    _Pragma("unroll") for (int j_ = 0; j_ < 2; ++j_) { \
      const int idx_ = (w << 1) + j_; \
      const int grp_ = (idx_ < 6 ? idx_ : idx_ + 6) + (s_) * 6; \
      const unsigned short* g_ = Bb + (bn + grp_ * 8 + srow) * (long)ldb + (k_) * 64 + schunk; \
      __builtin_amdgcn_global_load_lds((gmem_void*)g_, (lds_void*)(lds + (p_) * 28672 + 16384 + grp_ * 512), 16, 0, 0); \
    } \
  } else { \
    const int idx_ = w + 4; \
    const int grp_ = (idx_ < 6 ? idx_ : idx_ + 6) + (s_) * 6; \
    const unsigned short* g_ = Bb + (bn + grp_ * 8 + srow) * (long)ldb + (k_) * 64 + schunk; \
    __builtin_amdgcn_global_load_lds((gmem_void*)g_, (lds_void*)(lds + (p_) * 28672 + 16384 + grp_ * 512), 16, 0, 0); \
  } } while (0)

  const int nk = K / 64;
  WSTG_A(0, 0, 0); WSTG_A(0, 1, 0); WSTG_B(0, 0, 0); WSTG_B(0, 1, 0);
  WSTG_A(1, 0, 1); WSTG_A(1, 1, 1); WSTG_B(1, 0, 1); WSTG_B(1, 1, 1);
  WAITV(6);
  __builtin_amdgcn_s_barrier();

  for (int k = 0; k < nk; ++k) {
    const int p = k & 1;
    short8 af[2][2], bf0[3][2], bf1[3][2];
#pragma unroll
    for (int r = 0; r < 2; ++r)
#pragma unroll
      for (int ks = 0; ks < 2; ++ks) {
        const int arow = wm * 64 + r * 16 + fr;
        af[r][ks] = *(const short8*)(lds + p * 28672 + arow * 64 +
                                     ((((ks << 2) + kq) ^ (arow & 7)) << 3));
      }
#pragma unroll
    for (int c = 0; c < 3; ++c)
#pragma unroll
      for (int ks = 0; ks < 2; ++ks) {
        const int brow = wn * 96 + c * 16 + fr;
        bf0[c][ks] = *(const short8*)(lds + p * 28672 + 16384 + brow * 64 +
                                      ((((ks << 2) + kq) ^ (brow & 7)) << 3));
      }
    if (k >= 1 && k + 1 < nk) WSTG_A((k + 1) & 1, 1, k + 1);
    __builtin_amdgcn_s_barrier();
    __builtin_amdgcn_s_setprio(1);
#pragma unroll
    for (int ks = 0; ks < 2; ++ks)
#pragma unroll
      for (int r = 0; r < 2; ++r)
#pragma unroll
        for (int c = 0; c < 3; ++c)
          acc[r][c] = __builtin_amdgcn_mfma_f32_16x16x32_bf16(
              af[r][ks], bf0[c][ks], acc[r][c], 0, 0, 0);
    __builtin_amdgcn_s_setprio(0);
    __builtin_amdgcn_s_barrier();

#pragma unroll
    for (int c = 0; c < 3; ++c)
#pragma unroll
      for (int ks = 0; ks < 2; ++ks) {
        const int brow = wn * 96 + 48 + c * 16 + fr;
        bf1[c][ks] = *(const short8*)(lds + p * 28672 + 16384 + brow * 64 +
                                      ((((ks << 2) + kq) ^ (brow & 7)) << 3));
      }
    if (k >= 1 && k + 1 < nk) WSTG_B((k + 1) & 1, 1, k + 1);
    __builtin_amdgcn_s_barrier();
    __builtin_amdgcn_s_setprio(1);
#pragma unroll
    for (int ks = 0; ks < 2; ++ks)
#pragma unroll
      for (int r = 0; r < 2; ++r)
#pragma unroll
        for (int c = 0; c < 3; ++c)
          acc[r][3 + c] = __builtin_amdgcn_mfma_f32_16x16x32_bf16(
              af[r][ks], bf1[c][ks], acc[r][3 + c], 0, 0, 0);
    __builtin_amdgcn_s_setprio(0);
    __builtin_amdgcn_s_barrier();

#pragma unroll
    for (int r = 0; r < 2; ++r)
#pragma unroll
      for (int ks = 0; ks < 2; ++ks) {
        const int arow = wm * 64 + 32 + r * 16 + fr;
        af[r][ks] = *(const short8*)(lds + p * 28672 + arow * 64 +
                                     ((((ks << 2) + kq) ^ (arow & 7)) << 3));
      }
    if (k + 2 < nk) WSTG_A(p, 0, k + 2);
    __builtin_amdgcn_s_barrier();
    __builtin_amdgcn_s_setprio(1);
#pragma unroll
    for (int ks = 0; ks < 2; ++ks)
#pragma unroll
      for (int r = 0; r < 2; ++r)
#pragma unroll
        for (int c = 0; c < 3; ++c)
          acc[2 + r][c] = __builtin_amdgcn_mfma_f32_16x16x32_bf16(
              af[r][ks], bf0[c][ks], acc[2 + r][c], 0, 0, 0);
    __builtin_amdgcn_s_setprio(0);
    __builtin_amdgcn_s_barrier();

    if (k + 2 < nk) WSTG_B(p, 0, k + 2);
    __builtin_amdgcn_s_barrier();
    __builtin_amdgcn_s_setprio(1);
#pragma unroll
    for (int ks = 0; ks < 2; ++ks)
#pragma unroll
      for (int r = 0; r < 2; ++r)
#pragma unroll
        for (int c = 0; c < 3; ++c)
          acc[2 + r][3 + c] = __builtin_amdgcn_mfma_f32_16x16x32_bf16(
              af[r][ks], bf1[c][ks], acc[2 + r][3 + c], 0, 0, 0);
    __builtin_amdgcn_s_setprio(0);
    if (k + 1 < nk) {
      if (k + 2 < nk) WAITV(3);
      else            WAITV(0);
    }
    __builtin_amdgcn_s_barrier();
  }
#undef WSTG_A
#undef WSTG_B

  const int cr0 = (lane >> 4) * 4, cc = lane & 15;
#pragma unroll
  for (int mr = 0; mr < 4; ++mr)
#pragma unroll
    for (int nc = 0; nc < 6; ++nc)
#pragma unroll
      for (int j = 0; j < 4; ++j) {
        long row = bm + wm * 64 + mr * 16 + cr0 + j;
        long col = bn + wn * 96 + nc * 16 + cc;
        float v = acc[mr][nc][j] * scale;
        if (BIAS_MODE == 1) v += bias[z * bias_bs + col];
        long off = (long)z * c_bs + row * (long)ldc + col;
        if (OUT_BF16) ((unsigned short*)Cv)[off] = f2bf(v);
        else          ((float*)Cv)[off] = v;
      }
}

// ---- launch 2: G full 256x128 (0..143) + F (144..152) + c1,a2 (153..176) + s (177..184)
__global__ __launch_bounds__(512, 1) void gf_k(
    const unsigned short* xt, unsigned short* G,
    const unsigned short* wqtb, const unsigned short* wktb, unsigned short* F,
    const float* bq, const float* bk, const float* partials,
    float* c1v, float* a2v, float* sv)
{
  __shared__ unsigned short lds[73728];
  const int bid = blockIdx.x, tid = threadIdx.x;
  if (bid < 144) {
    const int z = bid & 7, t = bid >> 3;
    gemm_hn_core<0, 1>(z, (long)(t / 6) * 256, (long)(t % 6) * 128, lds,
        xt, xt, nullptr, nullptr, nullptr, nullptr, G,
        2048, 2048, 2048, 768, 768L * 2048, 768L * 2048, 768L * 768, 0, 1.0f);
  } else if (bid < 153) {
    const int t = bid - 144;
    gemm256_core<0, 1>(0, (long)(t / 3) * 256, (long)(t % 3) * 256, lds,
        wqtb, wktb, nullptr, nullptr, nullptr, nullptr, F,
        768, 768, 768, 768, 0, 0, 0, 0, 1.0f);
  } else if (bid < 177) {
    const int wid = tid >> 6, lane = tid & 63;
    const int r0 = (bid - 153) * 32;
#pragma unroll
    for (int mi = 0; mi < 4; ++mi) {
      const int r = r0 + wid * 4 + mi;
      const unsigned short* rk = wktb + (long)r * 768;
      const unsigned short* rq = wqtb + (long)r * 768;
      float ac = 0.f, aa = 0.f;
#pragma unroll
      for (int i = 0; i < 12; ++i) {
        const int k = lane + i * 64;
        ac += bf2f(rk[k]) * bq[k];
        aa += bf2f(rq[k]) * bk[k];
      }
      ac = wave_red(ac); aa = wave_red(aa);
      if (lane == 0) { c1v[r] = ac; a2v[r] = aa; }
    }
  } else {
    const int z = bid - 177;
    for (int d = tid; d < 768; d += 512) {
      const float* pp = partials + ((long)z * 768 + d) * 32;
      float s = 0.f;
#pragma unroll
      for (int j = 0; j < 32; ++j) s += pp[j];
      sv[z * 768 + d] = s;
    }
  }
}

// ---- launch 3: H = F·G 256x128 (0..143) + a1/w/g GEMVs (144..719) ----------
__global__ __launch_bounds__(512, 1) void hv_k(
    const unsigned short* Fb, const unsigned short* G, unsigned short* H,
    const float* Wv, const float* sv, const float* c1v,
    float* a1v, float* wvv, float* gv)
{
  __shared__ unsigned short lds[73728];
  const int bid = blockIdx.x, tid = threadIdx.x;
  if (bid < 144) {
    const int z = bid & 7, t = bid >> 3;
    gemm_hn_core<0, 1>(z, (long)(t / 6) * 256, (long)(t % 6) * 128, lds,
        Fb, G, nullptr, nullptr, nullptr, nullptr, H,
        768, 768, 768, 768, 0, 768L * 768, 768L * 768, 0, 1.0f);
  } else {
    const int t = bid - 144;
    const int type = t / 192, u = t % 192;
    const int z = u / 24, r0 = (u % 24) * 32;
    const int wid = tid >> 6, lane = tid & 63;
#pragma unroll
    for (int mi = 0; mi < 4; ++mi) {
      const int r = r0 + wid * 4 + mi;
      float a = 0.f;
      if (type == 0) {
        const unsigned short* row = Fb + (long)r * 768;
        const float* vec = sv + z * 768;
#pragma unroll
        for (int i = 0; i < 12; ++i) {
          const int k = lane + i * 64;
          a += bf2f(row[k]) * vec[k];
        }
      } else if (type == 1) {
        const float* row = Wv + (long)r * 768;
        const float* vec = sv + z * 768;
#pragma unroll
        for (int i = 0; i < 12; ++i) {
          const int k = lane + i * 64;
          a += row[k] * vec[k];
        }
      } else {
        const unsigned short* row = G + (long)z * 589824 + (long)r * 768;
#pragma unroll
        for (int i = 0; i < 12; ++i) {
          const int k = lane + i * 64;
          a += bf2f(row[k]) * c1v[k];
        }
      }
      a = wave_red(a);
      if (lane == 0) {
        if (type == 0) a1v[z * 768 + r] = a;
        else if (type == 1) wvv[z * 768 + r] = a;
        else gv[z * 768 + r] = a;
      }
    }
  }
}

// ---- launch 4: Pt 256x128 (0..143) + r blocks (144..335) -------------------
__global__ __launch_bounds__(512, 1) void pt_k(
    const unsigned short* wvb, const unsigned short* H, unsigned short* Pt,
    const float* bv, const float* a1v, const float* wvv, const float* a2v,
    const float* Wv, const float* gv, const float* c1v, const float* sv,
    const float* bq, const float* bk, float* rv)
{
  __shared__ unsigned short lds[73728];
  const float inv_sqrt_d = 0.036084391824351615f;
  const int bid = blockIdx.x, tid = threadIdx.x;
  if (bid < 144) {
    const int z = bid & 7, t = bid >> 3;
    gemm_hn_core<3, 1>(z, (long)(t / 6) * 256, (long)(t % 6) * 128, lds,
        wvb, H, bv, a1v, wvv, a2v, Pt,
        768, 768, 768, 768, 0, 768L * 768, 768L * 768, 0, inv_sqrt_d);
  } else {
    float* red1 = (float*)lds;
    float* red2 = red1 + 512;
    const int u = bid - 144;
    const int z = u / 24, r0 = (u % 24) * 32;
    const int wid = tid >> 6, lane = tid & 63;
    float p1 = 0.f, p2 = 0.f;
    for (int d = tid; d < 768; d += 512) {
      p1 += c1v[d] * sv[z * 768 + d];
      p2 += bq[d] * bk[d];
    }
    red1[tid] = p1; red2[tid] = p2;
    __syncthreads();
    for (int st = 256; st > 0; st >>= 1) {
      if (tid < st) { red1[tid] += red1[tid + st]; red2[tid] += red2[tid + st]; }
      __syncthreads();
    }
    const float cs = red1[0], bb = red2[0];
#pragma unroll
    for (int mi = 0; mi < 4; ++mi) {
      const int o = r0 + wid * 4 + mi;
      const float* row = Wv + (long)o * 768;
      const float* vec = gv + z * 768;
      float a = 0.f;
#pragma unroll
      for (int i = 0; i < 12; ++i) {
        const int k = lane + i * 64;
        a += row[k] * vec[k];
      }
      a = wave_red(a);
      if (lane == 0)
        rv[z * 768 + o] = inv_sqrt_d *
            (a + cs * bv[o] + bb * (wvv[z * 768 + o] + 2048.0f * bv[o]));
    }
  }
}

// ---- launch 5: out = xb·Pt^T + r   (256x192 core, 256 blocks) --------------
__global__ __launch_bounds__(512, 1) void final_k(
    const unsigned short* xb, const unsigned short* Pt, const float* rv, float* out)
{
  __shared__ unsigned short lds[57344];   // 112 KiB
  const int z = blockIdx.x & 7, t = blockIdx.x >> 3;  // t 0..31
  gemm_wn_core<1, 0>(z, (long)(t >> 2) * 256, (long)(t & 3) * 192, lds,
      xb, Pt, rv, out,
      768, 768, 768, 768, 2048L * 768, 768L * 768, 2048L * 768, 768, 1.0f);
}

extern "C" void kernel_launch(void* const* d_in, const int* in_sizes, int n_in,
                              void* d_out, int out_size, void* d_ws, size_t ws_size,
                              hipStream_t stream) {
  const float* x  = (const float*)d_in[0];
  const float* Wq = (const float*)d_in[1];
  const float* bq = (const float*)d_in[2];
  const float* Wk = (const float*)d_in[3];
  const float* bk = (const float*)d_in[4];
  const float* Wv = (const float*)d_in[5];
  const float* bv = (const float*)d_in[6];
  float* out = (float*)d_out;

  const int Bsz = 8, L = 2048, D = 768;
  const long xN = (long)Bsz * L * D;
  const long wN = (long)D * D;
  const long D2 = wN;

  char* ws = (char*)d_ws;
  unsigned short* xt   = (unsigned short*)ws; ws += xN * 2;
  unsigned short* xb   = (unsigned short*)ws; ws += xN * 2;
  unsigned short* wqtb = (unsigned short*)ws; ws += wN * 2;
  unsigned short* wktb = (unsigned short*)ws; ws += wN * 2;
  unsigned short* wvb  = (unsigned short*)ws; ws += wN * 2;
  unsigned short* Fb   = (unsigned short*)ws; ws += wN * 2;
  unsigned short* regA = (unsigned short*)ws; ws += (long)Bsz * D2 * 2;  // G, later Pt
  unsigned short* regB = (unsigned short*)ws; ws += (long)Bsz * D2 * 2;  // H
  float* partials = (float*)ws; ws += (long)Bsz * D * 32 * 4;
  float* sv  = (float*)ws; ws += (long)Bsz * D * 4;
  float* c1v = (float*)ws; ws += (long)D * 4;
  float* a2v = (float*)ws; ws += (long)D * 4;
  float* a1v = (float*)ws; ws += (long)Bsz * D * 4;
  float* wvv = (float*)ws; ws += (long)Bsz * D * 4;
  float* gv  = (float*)ws; ws += (long)Bsz * D * 4;
  float* rv  = (float*)ws; ws += (long)Bsz * D * 4;

  preamble<<<dim3(4512), dim3(256), 0, stream>>>(x, Wq, Wk, Wv, xb, xt, wqtb, wktb, wvb, partials);

  gf_k<<<dim3(185), dim3(512), 0, stream>>>(xt, regA, wqtb, wktb, Fb,
                                            bq, bk, partials, c1v, a2v, sv);

  hv_k<<<dim3(720), dim3(512), 0, stream>>>(Fb, regA, regB, Wv, sv, c1v, a1v, wvv, gv);

  pt_k<<<dim3(336), dim3(512), 0, stream>>>(wvb, regB, regA, bv, a1v, wvv, a2v,
                                            Wv, gv, c1v, sv, bq, bk, rv);

  final_k<<<dim3(256), dim3(512), 0, stream>>>(xb, regA, rv, out);

  (void)in_sizes; (void)n_in; (void)out_size; (void)ws_size;
}